// Round 9
// baseline (63.907 us; speedup 1.0000x reference)
//
#include <hip/hip_runtime.h>
#include <math.h>
#include <stdint.h>

// Problem constants: B=8, S=4096, D=1024, Q=16 -> 32768 rows
#define ROWS_TOTAL 32768
#define DDIM 1024
#define QDIM 16

typedef __attribute__((ext_vector_type(8))) short bf16x8;  // 8 bf16 (4 VGPRs)
typedef __attribute__((ext_vector_type(4))) float f32x4;   // 4 f32

union ABfrag { uint32_t u[4]; bf16x8 v; };

// pack the high 16 bits (truncated bf16) of two f32 bit patterns:
// result low ushort = a.hi16 (lower-k element), high ushort = b.hi16
__device__ __forceinline__ uint32_t packhi(uint32_t a, uint32_t b) {
  return __builtin_amdgcn_perm(b, a, 0x07060302u);
}

// ============================================================
// Kernel Z (MFMA, split-K, PERSISTENT 4-tile pipeline):
//   z[row][q] = cos(relu(x[row]@W1 + b1) + theta)
//
// r4-r8 all shared one structure: block = load-everything -> one
// latency round-trip -> compute -> die, repeated 8x per CU with no
// overlap. This round: 512 blocks x 4 tiles (16 rows each), software-
// pipelined ACROSS tiles inside the block:
//   steady state per tile t (2 raw barriers, vmcnt NEVER drained):
//     ds_read frags(t) ; lgkmcnt(0) ; barrier
//     ds_write xs <- st (tile t+1, reg-staged)  [T14 write-late]
//     issue global loads tile t+2 -> st         [T14 issue-early]
//     MFMA(t) (12x mfma_16x16x32_bf16, split-bf16 3-term)
//     red-write ; lgkmcnt(0) ; barrier ; spread epilogue(t)
//   - W1 fragments loaded+converted ONCE per block (was once/tile).
//   - Raw s_barrier + lgkmcnt-only waits: t+2 loads stay in flight
//     across barriers (counted vmcnt emitted by compiler on reg dep).
//   - Epilogue spread over all 8 waves (wave w: rows 2w,2w+1).
// Fragment maps (verified r4-r8, random data):
//   A: lane l -> row l&15; B: lane l -> col l&15 (same k-perm both);
//   C: lane l -> D[(l>>4)*4+i][l&15]
// LDS 72KB; VGPR target <=128 -> 2 blocks/CU = 16 waves/CU.
// ============================================================
#define ZTPB 512
#define ZWPB 8
#define ZTILES 4
#define ZNBLOCKS (ROWS_TOTAL / (16 * ZTILES))   // 512

__global__ __launch_bounds__(ZTPB, 4)
void z_kernel(const float* __restrict__ x, const float* __restrict__ W1,
              const float* __restrict__ b1, const float* __restrict__ theta,
              float* __restrict__ z, int zstride) {
  const int t    = threadIdx.x;
  const int lane = t & 63;
  const int wid  = t >> 6;     // k-slice owner, 0..7
  const int g    = lane >> 4;  // lane-group
  const int q5   = lane & 15;

  __shared__ __align__(16) float xs[16][DDIM];      // 64 KB, swizzled 16B units
  __shared__ __align__(16) float red[ZWPB][64][4];  // 8 KB partial buffer

  const int tile0 = blockIdx.x * ZTILES;
  const int kb    = wid * 128;  // this wave's k-base (floats)

  const float bq = b1[q5];
  const float tq = theta[q5];

  // ---- W1 slice -> registers, ONCE per block (L2-hot scalar loads)
  ABfrag bhi[4], blo[4];
  {
    float wf[4][8];
#pragma unroll
    for (int s = 0; s < 4; ++s) {
      const float* wp = W1 + (size_t)(kb + 32 * s + 4 * g) * QDIM + q5;
#pragma unroll
      for (int j = 0; j < 4; ++j) wf[s][j] = wp[(size_t)j * QDIM];
#pragma unroll
      for (int j = 0; j < 4; ++j) wf[s][4 + j] = wp[(size_t)(16 + j) * QDIM];
    }
#pragma unroll
    for (int s = 0; s < 4; ++s) {
      uint32_t u[8], lo[8];
#pragma unroll
      for (int j = 0; j < 8; ++j) {
        u[j]  = __float_as_uint(wf[s][j]);
        lo[j] = __float_as_uint(wf[s][j] - __uint_as_float(u[j] & 0xFFFF0000u));
      }
      bhi[s].u[0] = packhi(u[0], u[1]);   bhi[s].u[1] = packhi(u[2], u[3]);
      bhi[s].u[2] = packhi(u[4], u[5]);   bhi[s].u[3] = packhi(u[6], u[7]);
      blo[s].u[0] = packhi(lo[0], lo[1]); blo[s].u[1] = packhi(lo[2], lo[3]);
      blo[s].u[2] = packhi(lo[4], lo[5]); blo[s].u[3] = packhi(lo[6], lo[7]);
    }
  }

  // ---- staging helpers: wave w owns rows 2w,2w+1 of the current tile
  const int rs = 2 * wid;
  f32x4 st[8];
  auto load_tile = [&](int tile) {
#pragma unroll
    for (int rr = 0; rr < 2; ++rr) {
      const float* xp = x + (size_t)(tile * 16 + rs + rr) * DDIM;
#pragma unroll
      for (int p = 0; p < 4; ++p)
        st[rr * 4 + p] =
            *reinterpret_cast<const f32x4*>(xp + 4 * (64 * p + lane));
    }
  };
  auto store_tile = [&]() {
#pragma unroll
    for (int rr = 0; rr < 2; ++rr) {
      const int r = rs + rr;
#pragma unroll
      for (int p = 0; p < 4; ++p) {
        const int u = 64 * p + lane;  // 16B unit within the row
        *reinterpret_cast<f32x4*>(&xs[r][4 * (u ^ (r & 7))]) = st[rr * 4 + p];
      }
    }
  };

  // ---- prologue: xs <- tile0; st <- tile1 (loads left in flight)
  load_tile(tile0);
  store_tile();
  load_tile(tile0 + 1);
  asm volatile("s_waitcnt lgkmcnt(0)" ::: "memory");
  __builtin_amdgcn_s_barrier();

  const int ub = 32 * wid;
  const int rr_f = lane & 15;       // fragment row
  const int swz = rr_f & 7;

  for (int tt = 0; tt < ZTILES; ++tt) {
    const int row0 = (tile0 + tt) * 16;

    // ---- fragments of tile tt from xs (bank-balanced via XOR swizzle)
    float4 a0[4], a1[4];
#pragma unroll
    for (int s = 0; s < 4; ++s) {
      a0[s] = *reinterpret_cast<const float4*>(
          &xs[rr_f][4 * ((ub + 8 * s + g) ^ swz)]);
      a1[s] = *reinterpret_cast<const float4*>(
          &xs[rr_f][4 * ((ub + 8 * s + 4 + g) ^ swz)]);
    }
    asm volatile("s_waitcnt lgkmcnt(0)" ::: "memory");
    __builtin_amdgcn_s_barrier();   // xs reads done -> xs reusable

    // ---- pipeline: write tile tt+1 into xs, then launch tile tt+2 loads
    if (tt + 1 < ZTILES) {
      store_tile();                 // waits st's loads via reg deps (vmcnt)
      if (tt + 2 < ZTILES) load_tile(tile0 + tt + 2);
    }

    // ---- MFMA over this wave's k-slice (regs only; overlaps loads)
    f32x4 acc = {0.f, 0.f, 0.f, 0.f};
#pragma unroll
    for (int s = 0; s < 4; ++s) {
      const float fv[8] = {a0[s].x, a0[s].y, a0[s].z, a0[s].w,
                           a1[s].x, a1[s].y, a1[s].z, a1[s].w};
      uint32_t u[8], lo[8];
#pragma unroll
      for (int j = 0; j < 8; ++j) {
        u[j]  = __float_as_uint(fv[j]);
        lo[j] = __float_as_uint(fv[j] - __uint_as_float(u[j] & 0xFFFF0000u));
      }
      ABfrag ahi, alo;
      ahi.u[0] = packhi(u[0], u[1]);   ahi.u[1] = packhi(u[2], u[3]);
      ahi.u[2] = packhi(u[4], u[5]);   ahi.u[3] = packhi(u[6], u[7]);
      alo.u[0] = packhi(lo[0], lo[1]); alo.u[1] = packhi(lo[2], lo[3]);
      alo.u[2] = packhi(lo[4], lo[5]); alo.u[3] = packhi(lo[6], lo[7]);

      acc = __builtin_amdgcn_mfma_f32_16x16x32_bf16(ahi.v, bhi[s].v, acc, 0, 0, 0);
      acc = __builtin_amdgcn_mfma_f32_16x16x32_bf16(alo.v, bhi[s].v, acc, 0, 0, 0);
      acc = __builtin_amdgcn_mfma_f32_16x16x32_bf16(ahi.v, blo[s].v, acc, 0, 0, 0);
    }

    // ---- split-K combine + spread epilogue
    *reinterpret_cast<f32x4*>(&red[wid][lane][0]) = acc;
    asm volatile("s_waitcnt lgkmcnt(0)" ::: "memory");
    __builtin_amdgcn_s_barrier();   // red + xs(t+1) writes visible

    if (lane < 32) {                // wave w finishes rows 2w, 2w+1
      const int rr = rs + ((lane >> 4) & 1);
      const int l2 = (rr >> 2) * 16 + q5;
      float ssum = 0.f;
#pragma unroll
      for (int j = 0; j < ZWPB; ++j) ssum += red[j][l2][rr & 3];
      const float sv = fmaxf(ssum + bq, 0.f) + tq;
      z[(size_t)(row0 + rr) * zstride + q5] = __cosf(sv);
    }
    // next red-write happens only after the next barrier -> no race
  }
}

// ============================================================
// Kernel O: out[row] = z[row] @ W2 + b2  (unchanged; ~5 us, writes
//   L3-absorbed). z/out intentionally NOT __restrict__ (aliased fallback).
// ============================================================
#define OTPB 256
#define ORPB 16
#define ONBLOCKS (ROWS_TOTAL / ORPB)  // 2048

__global__ __launch_bounds__(OTPB, 4)
void o_kernel(const float* z, int zstride, const float* __restrict__ W2,
              const float* __restrict__ b2, float* out) {
  const int t   = threadIdx.x;
  const int col = 4 * t;

  float4 w2r[QDIM];
#pragma unroll
  for (int q = 0; q < QDIM; ++q)
    w2r[q] = *reinterpret_cast<const float4*>(W2 + (size_t)q * DDIM + col);
  const float4 bb = *reinterpret_cast<const float4*>(b2 + col);

  const int row0 = blockIdx.x * ORPB;

  const float* zp0 = z + (size_t)row0 * zstride;
  float4 zc0 = *reinterpret_cast<const float4*>(zp0 + 0);
  float4 zc1 = *reinterpret_cast<const float4*>(zp0 + 4);
  float4 zc2 = *reinterpret_cast<const float4*>(zp0 + 8);
  float4 zc3 = *reinterpret_cast<const float4*>(zp0 + 12);

#pragma unroll
  for (int r = 0; r < ORPB; ++r) {
    float4 zn0 = zc0, zn1 = zc1, zn2 = zc2, zn3 = zc3;
    if (r + 1 < ORPB) {
      const float* znp = z + (size_t)(row0 + r + 1) * zstride;
      zn0 = *reinterpret_cast<const float4*>(znp + 0);
      zn1 = *reinterpret_cast<const float4*>(znp + 4);
      zn2 = *reinterpret_cast<const float4*>(znp + 8);
      zn3 = *reinterpret_cast<const float4*>(znp + 12);
    }

    const float zv[16] = {zc0.x, zc0.y, zc0.z, zc0.w,
                          zc1.x, zc1.y, zc1.z, zc1.w,
                          zc2.x, zc2.y, zc2.z, zc2.w,
                          zc3.x, zc3.y, zc3.z, zc3.w};
    float4 acc = bb;
#pragma unroll
    for (int q = 0; q < QDIM; ++q) {
      acc.x = fmaf(zv[q], w2r[q].x, acc.x);
      acc.y = fmaf(zv[q], w2r[q].y, acc.y);
      acc.z = fmaf(zv[q], w2r[q].z, acc.z);
      acc.w = fmaf(zv[q], w2r[q].w, acc.w);
    }
    *reinterpret_cast<float4*>(out + (size_t)(row0 + r) * DDIM + col) = acc;

    zc0 = zn0; zc1 = zn1; zc2 = zn2; zc3 = zn3;
  }
}

extern "C" void kernel_launch(void* const* d_in, const int* in_sizes, int n_in,
                              void* d_out, int out_size, void* d_ws, size_t ws_size,
                              hipStream_t stream) {
  const float* x     = (const float*)d_in[0];
  const float* W1    = (const float*)d_in[1];
  const float* b1    = (const float*)d_in[2];
  const float* theta = (const float*)d_in[3];
  const float* W2    = (const float*)d_in[4];
  const float* b2    = (const float*)d_in[5];
  float* out = (float*)d_out;

  const size_t zbytes = (size_t)ROWS_TOTAL * QDIM * sizeof(float);  // 2 MB
  float* zbuf;
  int zstride;
  if (d_ws != nullptr && ws_size >= zbytes) {
    zbuf = (float*)d_ws;  // compact z in workspace
    zstride = QDIM;
  } else {
    zbuf = out;           // fallback: stash z in out[row][0:16]
    zstride = DDIM;
  }

  z_kernel<<<dim3(ZNBLOCKS), dim3(ZTPB), 0, stream>>>(x, W1, b1, theta, zbuf, zstride);
  o_kernel<<<dim3(ONBLOCKS), dim3(OTPB), 0, stream>>>(zbuf, zstride, W2, b2, out);
}